// Round 5
// baseline (44.589 us; speedup 1.0000x reference)
//
#include <hip/hip_runtime.h>

// Problem constants (B=131072 rows, C=64 cols)
#define NROWS 131072
#define NCOLS 64
// kernF (focal): pure stream
#define FBLK 2048
#define FTHR 256             // 524288 threads, 4 float4-pairs each
// kernG (Gram): mask/popcount
#define GBLK 512
#define GTHR 512             // 8 waves
#define GWAVES 8
#define ROWS_PER_WAVE 32     // 512 * 8 * 32 = 131072
#define PK_CELLS 4096        // packed u16-pair cells per block (2048 S + 2048 P)
#define NGRP 16              // B1 groups (32 source blocks each)

// Workspace layout:
//   [0]       float  pkF[2048]            (per-block focal sums, 8 KB)
//   [8192]    u32    red[16][2][64][64]   (512 KB)
//   [532480]  u32    pk[512][4096]        (8 MB)

// -------- Kernel F: focal loss only (pure memory stream) --------
__global__ __launch_bounds__(FTHR, 6)
void kernF(const float* __restrict__ in, const float* __restrict__ tg,
           const float* __restrict__ pw, float* __restrict__ pkF) {
    const int tid = threadIdx.x;
    const int gtid = blockIdx.x * FTHR + tid;
    const int c4 = (gtid & 15) * 4;          // stride 524288 % 16 == 0: constant
    const float4 pw4 = *reinterpret_cast<const float4*>(pw + c4);
    const float4* in4 = reinterpret_cast<const float4*>(in);
    const float4* tg4 = reinterpret_cast<const float4*>(tg);

    // issue all 8 loads up front
    float4 xr[4], tr[4];
#pragma unroll
    for (int k = 0; k < 4; ++k) xr[k] = in4[(size_t)gtid + (size_t)k * (FBLK * FTHR)];
#pragma unroll
    for (int k = 0; k < 4; ++k) tr[k] = tg4[(size_t)gtid + (size_t)k * (FBLK * FTHR)];

    float fsum = 0.f;
    auto elem = [&](float x, float t, float pwc) {
        float ax = fabsf(x);
        float e = __expf(-ax);                        // exp(-|x|)
        float L = __logf(1.f + e);                    // log1p(exp(-|x|)), stable
        float inv = __builtin_amdgcn_rcpf(1.f + e);   // sigmoid(|x|)
        float qq = e * inv;                           // 1 - sigmoid(|x|)
        bool tb = t > 0.5f;
        bool pb = x >= 0.f;
        float w = (tb == pb) ? qq : inv;              // 1 - p_t
        float bce = tb ? pwc * (L + fmaxf(-x, 0.f)) : (L + fmaxf(x, 0.f));
        fsum += w * w * bce;
    };
#pragma unroll
    for (int k = 0; k < 4; ++k) {
        elem(xr[k].x, tr[k].x, pw4.x);
        elem(xr[k].y, tr[k].y, pw4.y);
        elem(xr[k].z, tr[k].z, pw4.z);
        elem(xr[k].w, tr[k].w, pw4.w);
    }

#pragma unroll
    for (int off = 32; off; off >>= 1) fsum += __shfl_down(fsum, off, 64);
    __shared__ float fp[4];
    const int lane = tid & 63, wv = tid >> 6;
    if (lane == 0) fp[wv] = fsum;
    __syncthreads();
    if (tid == 0) pkF[blockIdx.x] = fp[0] + fp[1] + fp[2] + fp[3];
}

// -------- Kernel G: Gram only (S = t^T t, P = v^T w), reads from L3 --------
// Identical mask/readlane structure to the verified round-4 kernel, focal
// math stripped. Lane l: cols c4=4*(l&15)..+3, rows row0+h+4q via float4;
// disjoint bit 4q+h; shfl_xor(16|32) OR-combine; lane owns column jc=c4+h.
template<bool ATOMIC_FLUSH>
__global__ __launch_bounds__(GTHR, 2)
void kernG(const float* __restrict__ in, const float* __restrict__ tg,
           unsigned* __restrict__ pk,
           unsigned* __restrict__ gS, unsigned* __restrict__ gP) {
    __shared__ unsigned ldsSP[PK_CELLS];   // [0..2047]=S packed, [2048..4095]=P
    const int tid = threadIdx.x;
#pragma unroll
    for (int k = tid; k < PK_CELLS; k += GTHR) ldsSP[k] = 0u;
    __syncthreads();

    const int lane = tid & 63;
    const int wv = tid >> 6;                 // 0..7
    const int h = lane >> 4;                 // row phase 0..3
    const int c4 = (lane & 15) * 4;
    const int jc = c4 + h;                   // this lane's owned column
    const int row0 = blockIdx.x * (GWAVES * ROWS_PER_WAVE) + wv * ROWS_PER_WAVE;

    const float4* inp = reinterpret_cast<const float4*>(in)
                        + (size_t)(row0 + h) * 16 + (lane & 15);
    const float4* tgp = reinterpret_cast<const float4*>(tg)
                        + (size_t)(row0 + h) * 16 + (lane & 15);

    float4 xr[8], tr[8];
#pragma unroll
    for (int q = 0; q < 8; ++q) xr[q] = inp[(size_t)q * 64];  // stride 4 rows
#pragma unroll
    for (int q = 0; q < 8; ++q) tr[q] = tgp[(size_t)q * 64];

    unsigned m4[4] = {0u, 0u, 0u, 0u};
    unsigned v4[4] = {0u, 0u, 0u, 0u};
    const unsigned hbit = 1u << h;

    auto bits = [&](float x, float t, unsigned bq, unsigned& mk, unsigned& vk) {
        bool tb = t > 0.5f;
        bool pb = x >= 0.f;
        mk |= tb ? bq : 0u;
        vk |= (tb && pb) ? bq : 0u;
    };
#pragma unroll
    for (int q = 0; q < 8; ++q) {            // rows row0 + h + 4q, bit 4q+h
        const unsigned bq = hbit << (4 * q);
        bits(xr[q].x, tr[q].x, bq, m4[0], v4[0]);
        bits(xr[q].y, tr[q].y, bq, m4[1], v4[1]);
        bits(xr[q].z, tr[q].z, bq, m4[2], v4[2]);
        bits(xr[q].w, tr[q].w, bq, m4[3], v4[3]);
    }

#pragma unroll
    for (int k = 0; k < 4; ++k) {
        m4[k] |= __shfl_xor(m4[k], 16, 64);
        m4[k] |= __shfl_xor(m4[k], 32, 64);
        v4[k] |= __shfl_xor(v4[k], 16, 64);
        v4[k] |= __shfl_xor(v4[k], 32, 64);
    }
    const unsigned m = (h & 2) ? ((h & 1) ? m4[3] : m4[2]) : ((h & 1) ? m4[1] : m4[0]);
    const unsigned v = (h & 2) ? ((h & 1) ? v4[3] : v4[2]) : ((h & 1) ? v4[1] : v4[0]);
    const unsigned wm = m & ~v;              // t=1 & pred=0

    // Gram: column a lives in lane ri = ((a&3)<<4) | (a>>2)
#pragma unroll
    for (int k = 0; k < 16; ++k) {
        unsigned aS = 0u, aP = 0u;
#pragma unroll
        for (int b = 0; b < 4; ++b) {
            const int ri = (b << 4) | k;     // lane owning column a = 4k+b
            unsigned mi = (unsigned)__builtin_amdgcn_readlane((int)m, ri);
            unsigned vi = (unsigned)__builtin_amdgcn_readlane((int)v, ri);
            aS += (unsigned)__popc(mi & m) << (8 * b);    // S[4k+b][jc]
            aP += (unsigned)__popc(vi & wm) << (8 * b);   // P[4k+b][jc]
        }
        atomicAdd(&ldsSP[(2 * k + 0) * 64 + jc],
                  (aS & 0xFFu) | (((aS >> 8) & 0xFFu) << 16));
        atomicAdd(&ldsSP[(2 * k + 1) * 64 + jc],
                  ((aS >> 16) & 0xFFu) | ((aS >> 24) << 16));
        atomicAdd(&ldsSP[2048 + (2 * k + 0) * 64 + jc],
                  (aP & 0xFFu) | (((aP >> 8) & 0xFFu) << 16));
        atomicAdd(&ldsSP[2048 + (2 * k + 1) * 64 + jc],
                  ((aP >> 16) & 0xFFu) | ((aP >> 24) << 16));
    }
    __syncthreads();

    if (!ATOMIC_FLUSH) {
        uint4* dst4 = reinterpret_cast<uint4*>(pk + (size_t)blockIdx.x * PK_CELLS);
        const uint4* src4 = reinterpret_cast<const uint4*>(ldsSP);
        dst4[tid] = src4[tid];               // 1024 uint4, 2 per thread
        dst4[tid + GTHR] = src4[tid + GTHR];
    } else {
        for (int k = tid; k < 2048; k += GTHR) {
            const int wrd = k >> 6, j = k & 63;
            const int i0 = 2 * wrd;
            unsigned s = ldsSP[k], p = ldsSP[2048 + k];
            atomicAdd(&gS[i0 * 64 + j], s & 0xFFFFu);
            atomicAdd(&gS[(i0 + 1) * 64 + j], s >> 16);
            atomicAdd(&gP[i0 * 64 + j], p & 0xFFFFu);
            atomicAdd(&gP[(i0 + 1) * 64 + j], p >> 16);
        }
    }
}

// -------- B1: reduce 512 block-partials into 16 group sums (uint4 loads) ----
__global__ __launch_bounds__(256)
void kernB1(const unsigned* __restrict__ pk, unsigned* __restrict__ red) {
    const int t = blockIdx.x * 256 + threadIdx.x;  // 0..16383 = 16 grp x 1024
    const int g = t >> 10;
    const int pc = (t & 1023) * 4;
    unsigned lo[4] = {0u, 0u, 0u, 0u}, hi[4] = {0u, 0u, 0u, 0u};
    const uint4* p = reinterpret_cast<const uint4*>(pk + (size_t)(g * 32) * PK_CELLS + pc);
#pragma unroll 8
    for (int b = 0; b < 32; ++b) {
        uint4 w = p[(size_t)b * (PK_CELLS / 4)];
        lo[0] += w.x & 0xFFFFu; hi[0] += w.x >> 16;
        lo[1] += w.y & 0xFFFFu; hi[1] += w.y >> 16;
        lo[2] += w.z & 0xFFFFu; hi[2] += w.z >> 16;
        lo[3] += w.w & 0xFFFFu; hi[3] += w.w >> 16;
    }
#pragma unroll
    for (int j = 0; j < 4; ++j) {
        const int pcj = pc + j;
        const int mat = pcj >> 11;           // 0=S, 1=P
        const int e = pcj & 2047;
        const int i0 = (e >> 6) * 2;         // word -> rows i0, i0+1
        const int col = e & 63;
        unsigned* o = red + ((size_t)g * 2 + mat) * 4096 + i0 * 64 + col;
        o[0] = lo[j];
        o[64] = hi[j];
    }
}

// -------- BC: fused final reduce + penalty + focal + output (1 block) ------
__global__ __launch_bounds__(1024)
void kernBC(const unsigned* __restrict__ red, const float* __restrict__ pkF,
            float* __restrict__ out) {
    const int tid = threadIdx.x;
    const int c4 = tid * 4;                  // 4096 cells / 1024 threads
    unsigned S[4] = {0u, 0u, 0u, 0u}, P[4] = {0u, 0u, 0u, 0u};
#pragma unroll
    for (int g = 0; g < NGRP; ++g) {
        uint4 s4 = *reinterpret_cast<const uint4*>(red + ((size_t)g * 2 + 0) * 4096 + c4);
        uint4 p4 = *reinterpret_cast<const uint4*>(red + ((size_t)g * 2 + 1) * 4096 + c4);
        S[0] += s4.x; S[1] += s4.y; S[2] += s4.z; S[3] += s4.w;
        P[0] += p4.x; P[1] += p4.y; P[2] += p4.z; P[3] += p4.w;
    }
    double acc = 0.0;
#pragma unroll
    for (int j = 0; j < 4; ++j) {
        const int i = (c4 + j) >> 6, col = (c4 + j) & 63;
        const float corr = (float)S[j] * (1.0f / (float)NROWS);
        // penalty_total = 2 * sum A_ij P_ij, A = 0.5*corr thresholded => corr*P
        if (i != col && corr > 0.3f) acc += (double)corr * (double)P[j];
    }
    acc += (double)pkF[tid] + (double)pkF[tid + 1024];
#pragma unroll
    for (int off = 32; off; off >>= 1) acc += __shfl_down(acc, off, 64);
    __shared__ double wred[16];
    const int lane = tid & 63, wv = tid >> 6;
    if (lane == 0) wred[wv] = acc;
    __syncthreads();
    if (tid < 16) {
        double tot = wred[tid];
#pragma unroll
        for (int off = 8; off; off >>= 1) tot += __shfl_down(tot, off, 64);
        if (tid == 0)
            out[0] = (float)(tot * (1.0 / (double)((size_t)NROWS * NCOLS)));
    }
}

// -------- Fallback finalize (atomic path) --------
__global__ __launch_bounds__(1024)
void kernW(const unsigned* __restrict__ gS, const unsigned* __restrict__ gP,
           const float* __restrict__ pkF, float* __restrict__ out) {
    const int tid = threadIdx.x;
    double acc = 0.0;
#pragma unroll
    for (int kk = 0; kk < 4; ++kk) {
        const int c = tid + kk * 1024;
        unsigned S = gS[c], P = gP[c];
        const int i = c >> 6, j = c & 63;
        const float corr = (float)S * (1.0f / (float)NROWS);
        if (i != j && corr > 0.3f) acc += (double)corr * (double)P;
    }
    acc += (double)pkF[tid] + (double)pkF[tid + 1024];
#pragma unroll
    for (int off = 32; off; off >>= 1) acc += __shfl_down(acc, off, 64);
    __shared__ double wred[16];
    const int lane = tid & 63, wv = tid >> 6;
    if (lane == 0) wred[wv] = acc;
    __syncthreads();
    if (tid < 16) {
        double tot = wred[tid];
#pragma unroll
        for (int off = 8; off; off >>= 1) tot += __shfl_down(tot, off, 64);
        if (tid == 0)
            out[0] = (float)(tot * (1.0 / (double)((size_t)NROWS * NCOLS)));
    }
}

extern "C" void kernel_launch(void* const* d_in, const int* in_sizes, int n_in,
                              void* d_out, int out_size, void* d_ws, size_t ws_size,
                              hipStream_t stream) {
    const float* in = (const float*)d_in[0];
    const float* tg = (const float*)d_in[1];
    const float* pw = (const float*)d_in[2];
    float* out = (float*)d_out;
    char* ws = (char*)d_ws;

    float* pkF = (float*)ws;                              // 8 KB
    unsigned* red = (unsigned*)(ws + 8192);               // 512 KB
    unsigned* pk = (unsigned*)(ws + 8192 + 524288);       // 8 MB
    const size_t need = 8192 + 524288 + (size_t)GBLK * PK_CELLS * sizeof(unsigned);

    kernF<<<FBLK, FTHR, 0, stream>>>(in, tg, pw, pkF);
    if (ws_size >= need) {
        kernG<false><<<GBLK, GTHR, 0, stream>>>(in, tg, pk, nullptr, nullptr);
        kernB1<<<(NGRP * 1024) / 256, 256, 0, stream>>>(pk, red);
        kernBC<<<1, 1024, 0, stream>>>(red, pkF, out);
    } else {
        // fallback: needs only ~41 KB of workspace
        unsigned* gS = (unsigned*)(ws + 8192);
        unsigned* gP = gS + 4096;
        hipMemsetAsync(ws + 8192, 0, 2 * 4096 * sizeof(unsigned), stream);
        kernG<true><<<GBLK, GTHR, 0, stream>>>(in, tg, nullptr, gS, gP);
        kernW<<<1, 1024, 0, stream>>>(gS, gP, pkF, out);
    }
}

// Round 6
// 38.509 us; speedup vs baseline: 1.1579x; 1.1579x over previous
//
#include <hip/hip_runtime.h>

// Problem constants (B=131072 rows, C=64 cols)
#define NROWS 131072
#define NCOLS 64
#define NBLK 512
#define NTHR 512             // 8 waves
#define NWAVES 8
#define ROWS_PER_WAVE 32     // 512 blocks * 8 waves * 32 rows = 131072
#define PK_CELLS 4096        // packed u16-pair cells per block (2048 S + 2048 P)
#define NGRP 16              // B1 groups (32 source blocks each)

// Workspace layout:
//   [0]       float  pkF[512]             (per-block focal sums, 2 KB)
//   [8192]    u32    red[16][2][64][64]   (512 KB)
//   [532480]  u32    pk[512][4096]        (8 MB)

// -------- Kernel A: fused focal + Gram (S = t^T t, P = v^T (t & ~v)) --------
// NO LDS ATOMICS (round-5 diagnosis: ds_atomic_add RMW throughput was the
// ~27 us serial resource in every prior round). Structure:
//   1. lane l: cols c4=4*(l&15)..+3, rows row0+h+4q (h=l>>4, q=0..7), float4,
//      all 16 loads issued up front; focal math + 32-bit column masks with
//      disjoint bits (4q+h), OR-combined via shfl_xor(16|32); lane owns
//      column jc=c4+h (permutation of 0..63).
//   2. masks published to a 4KB LDS buffer indexed by TRUE column (jc), one
//      plain ds_write_b64 per lane; one barrier. The jc-permutation vanishes
//      after the LDS round-trip.
//   3. wave wv computes output rows a=8*wv..8*wv+7 only (no duplication):
//      per source-wave ww: per-lane read (mw,vw)=maskbuf[ww][lane], 8 uniform
//      broadcast reads maskbuf[ww][8*wv+r]; aS[r]+=popc(mi&mw),
//      aP[r]+=popc(vi&(mw&~vw)). Counts <= 256.
//   4. u16-pair pack (rows 2w,2w+1 per word) -> coalesced global store in the
//      exact pk format the verified B1/BC backend expects.
template<bool ATOMIC_FLUSH>
__global__ __launch_bounds__(NTHR, 2)
void kernA(const float* __restrict__ in, const float* __restrict__ tg,
           const float* __restrict__ pw,
           unsigned* __restrict__ pk, float* __restrict__ pkF,
           unsigned* __restrict__ gS, unsigned* __restrict__ gP) {
    __shared__ unsigned maskbuf[NWAVES][64][2];   // [wave][col][m,v]  4 KB
    __shared__ float fpart[NWAVES];
    const int tid = threadIdx.x;
    const int lane = tid & 63;
    const int wv = tid >> 6;                 // 0..7
    const int h = lane >> 4;                 // row phase 0..3
    const int c4 = (lane & 15) * 4;
    const int jc = c4 + h;                   // this lane's owned column
    const int row0 = blockIdx.x * (NWAVES * ROWS_PER_WAVE) + wv * ROWS_PER_WAVE;

    const float4 pw4 = *reinterpret_cast<const float4*>(pw + c4);
    const float4* inp = reinterpret_cast<const float4*>(in)
                        + (size_t)(row0 + h) * 16 + (lane & 15);
    const float4* tgp = reinterpret_cast<const float4*>(tg)
                        + (size_t)(row0 + h) * 16 + (lane & 15);

    // ---- issue ALL 16 loads first ----
    float4 xr[8], tr[8];
#pragma unroll
    for (int q = 0; q < 8; ++q) xr[q] = inp[(size_t)q * 64];  // stride 4 rows
#pragma unroll
    for (int q = 0; q < 8; ++q) tr[q] = tgp[(size_t)q * 64];

    float fsum = 0.f;
    unsigned m4[4] = {0u, 0u, 0u, 0u};
    unsigned v4[4] = {0u, 0u, 0u, 0u};
    const unsigned hbit = 1u << h;

    auto elem = [&](float x, float t, float pwc, unsigned bq, unsigned& mk, unsigned& vk) {
        float ax = fabsf(x);
        float e = __expf(-ax);                        // exp(-|x|)
        float L = __logf(1.f + e);                    // log1p(exp(-|x|)), stable
        float inv = __builtin_amdgcn_rcpf(1.f + e);   // sigmoid(|x|)
        float qq = e * inv;                           // 1 - sigmoid(|x|)
        bool tb = t > 0.5f;
        bool pb = x >= 0.f;
        float w = (tb == pb) ? qq : inv;              // 1 - p_t
        float bce = tb ? pwc * (L + fmaxf(-x, 0.f)) : (L + fmaxf(x, 0.f));
        fsum += w * w * bce;
        mk |= tb ? bq : 0u;
        vk |= (tb && pb) ? bq : 0u;
    };

#pragma unroll
    for (int q = 0; q < 8; ++q) {            // rows row0 + h + 4q, bit 4q+h
        const unsigned bq = hbit << (4 * q);
        elem(xr[q].x, tr[q].x, pw4.x, bq, m4[0], v4[0]);
        elem(xr[q].y, tr[q].y, pw4.y, bq, m4[1], v4[1]);
        elem(xr[q].z, tr[q].z, pw4.z, bq, m4[2], v4[2]);
        elem(xr[q].w, tr[q].w, pw4.w, bq, m4[3], v4[3]);
    }

    // OR-combine the 4 row-phases; bit b = row row0+b for that column
#pragma unroll
    for (int k = 0; k < 4; ++k) {
        m4[k] |= __shfl_xor(m4[k], 16, 64);
        m4[k] |= __shfl_xor(m4[k], 32, 64);
        v4[k] |= __shfl_xor(v4[k], 16, 64);
        v4[k] |= __shfl_xor(v4[k], 32, 64);
    }
    const unsigned m = (h & 2) ? ((h & 1) ? m4[3] : m4[2]) : ((h & 1) ? m4[1] : m4[0]);
    const unsigned v = (h & 2) ? ((h & 1) ? v4[3] : v4[2]) : ((h & 1) ? v4[1] : v4[0]);

    // publish masks (plain writes, true-column indexed); focal wave reduce
    maskbuf[wv][jc][0] = m;
    maskbuf[wv][jc][1] = v;
#pragma unroll
    for (int off = 32; off; off >>= 1) fsum += __shfl_down(fsum, off, 64);
    if (lane == 0) fpart[wv] = fsum;
    __syncthreads();

    if (tid == 0) {
        float tot = 0.f;
#pragma unroll
        for (int k = 0; k < NWAVES; ++k) tot += fpart[k];
        pkF[blockIdx.x] = tot;
    }

    // ---- slice Gram: wave wv owns output rows a = 8*wv .. 8*wv+7 ----
    unsigned aS[8] = {0u, 0u, 0u, 0u, 0u, 0u, 0u, 0u};
    unsigned aP[8] = {0u, 0u, 0u, 0u, 0u, 0u, 0u, 0u};
    const int a0 = wv * 8;
#pragma unroll
    for (int ww = 0; ww < NWAVES; ++ww) {
        const unsigned mw = maskbuf[ww][lane][0];   // column `lane`'s mask
        const unsigned vw = maskbuf[ww][lane][1];
        const unsigned wmw = mw & ~vw;              // t=1 & pred=0
#pragma unroll
        for (int r = 0; r < 8; ++r) {
            const unsigned mi = maskbuf[ww][a0 + r][0];   // uniform broadcast
            const unsigned vi = maskbuf[ww][a0 + r][1];
            aS[r] += (unsigned)__popc(mi & mw);           // S[a0+r][lane]
            aP[r] += (unsigned)__popc(vi & wmw);          // P[a0+r][lane]
        }
    }

    if (!ATOMIC_FLUSH) {
        // pack rows (2w, 2w+1) into u16 pairs; word-row w = 4*wv + r2
        unsigned* dst = pk + (size_t)blockIdx.x * PK_CELLS;
#pragma unroll
        for (int r2 = 0; r2 < 4; ++r2) {
            const int w = wv * 4 + r2;
            dst[w * 64 + lane] = aS[2 * r2] | (aS[2 * r2 + 1] << 16);
            dst[2048 + w * 64 + lane] = aP[2 * r2] | (aP[2 * r2 + 1] << 16);
        }
    } else {
#pragma unroll
        for (int r = 0; r < 8; ++r) {
            atomicAdd(&gS[(a0 + r) * 64 + lane], aS[r]);
            atomicAdd(&gP[(a0 + r) * 64 + lane], aP[r]);
        }
    }
}

// -------- B1: reduce 512 block-partials into 16 group sums (uint4 loads) ----
__global__ __launch_bounds__(256)
void kernB1(const unsigned* __restrict__ pk, unsigned* __restrict__ red) {
    const int t = blockIdx.x * 256 + threadIdx.x;  // 0..16383 = 16 grp x 1024
    const int g = t >> 10;
    const int pc = (t & 1023) * 4;
    unsigned lo[4] = {0u, 0u, 0u, 0u}, hi[4] = {0u, 0u, 0u, 0u};
    const uint4* p = reinterpret_cast<const uint4*>(pk + (size_t)(g * 32) * PK_CELLS + pc);
#pragma unroll 8
    for (int b = 0; b < 32; ++b) {
        uint4 w = p[(size_t)b * (PK_CELLS / 4)];
        lo[0] += w.x & 0xFFFFu; hi[0] += w.x >> 16;
        lo[1] += w.y & 0xFFFFu; hi[1] += w.y >> 16;
        lo[2] += w.z & 0xFFFFu; hi[2] += w.z >> 16;
        lo[3] += w.w & 0xFFFFu; hi[3] += w.w >> 16;
    }
#pragma unroll
    for (int j = 0; j < 4; ++j) {
        const int pcj = pc + j;
        const int mat = pcj >> 11;           // 0=S, 1=P
        const int e = pcj & 2047;
        const int i0 = (e >> 6) * 2;         // word -> rows i0, i0+1
        const int col = e & 63;
        unsigned* o = red + ((size_t)g * 2 + mat) * 4096 + i0 * 64 + col;
        o[0] = lo[j];
        o[64] = hi[j];
    }
}

// -------- BC: fused final reduce + penalty + focal + output (1 block) ------
__global__ __launch_bounds__(1024)
void kernBC(const unsigned* __restrict__ red, const float* __restrict__ pkF,
            float* __restrict__ out) {
    const int tid = threadIdx.x;
    const int c4 = tid * 4;                  // 4096 cells / 1024 threads
    unsigned S[4] = {0u, 0u, 0u, 0u}, P[4] = {0u, 0u, 0u, 0u};
#pragma unroll
    for (int g = 0; g < NGRP; ++g) {
        uint4 s4 = *reinterpret_cast<const uint4*>(red + ((size_t)g * 2 + 0) * 4096 + c4);
        uint4 p4 = *reinterpret_cast<const uint4*>(red + ((size_t)g * 2 + 1) * 4096 + c4);
        S[0] += s4.x; S[1] += s4.y; S[2] += s4.z; S[3] += s4.w;
        P[0] += p4.x; P[1] += p4.y; P[2] += p4.z; P[3] += p4.w;
    }
    double acc = 0.0;
#pragma unroll
    for (int j = 0; j < 4; ++j) {
        const int i = (c4 + j) >> 6, col = (c4 + j) & 63;
        const float corr = (float)S[j] * (1.0f / (float)NROWS);
        // penalty_total = 2 * sum A_ij P_ij, A = 0.5*corr thresholded => corr*P
        if (i != col && corr > 0.3f) acc += (double)corr * (double)P[j];
    }
    if (tid < NBLK) acc += (double)pkF[tid];
#pragma unroll
    for (int off = 32; off; off >>= 1) acc += __shfl_down(acc, off, 64);
    __shared__ double wred[16];
    const int lane = tid & 63, wv = tid >> 6;
    if (lane == 0) wred[wv] = acc;
    __syncthreads();
    if (tid < 16) {
        double tot = wred[tid];
#pragma unroll
        for (int off = 8; off; off >>= 1) tot += __shfl_down(tot, off, 64);
        if (tid == 0)
            out[0] = (float)(tot * (1.0 / (double)((size_t)NROWS * NCOLS)));
    }
}

// -------- Fallback finalize (atomic path) --------
__global__ __launch_bounds__(1024)
void kernW(const unsigned* __restrict__ gS, const unsigned* __restrict__ gP,
           const float* __restrict__ pkF, float* __restrict__ out) {
    const int tid = threadIdx.x;
    double acc = 0.0;
#pragma unroll
    for (int kk = 0; kk < 4; ++kk) {
        const int c = tid + kk * 1024;
        unsigned S = gS[c], P = gP[c];
        const int i = c >> 6, j = c & 63;
        const float corr = (float)S * (1.0f / (float)NROWS);
        if (i != j && corr > 0.3f) acc += (double)corr * (double)P;
    }
    if (tid < NBLK) acc += (double)pkF[tid];
#pragma unroll
    for (int off = 32; off; off >>= 1) acc += __shfl_down(acc, off, 64);
    __shared__ double wred[16];
    const int lane = tid & 63, wv = tid >> 6;
    if (lane == 0) wred[wv] = acc;
    __syncthreads();
    if (tid < 16) {
        double tot = wred[tid];
#pragma unroll
        for (int off = 8; off; off >>= 1) tot += __shfl_down(tot, off, 64);
        if (tid == 0)
            out[0] = (float)(tot * (1.0 / (double)((size_t)NROWS * NCOLS)));
    }
}

extern "C" void kernel_launch(void* const* d_in, const int* in_sizes, int n_in,
                              void* d_out, int out_size, void* d_ws, size_t ws_size,
                              hipStream_t stream) {
    const float* in = (const float*)d_in[0];
    const float* tg = (const float*)d_in[1];
    const float* pw = (const float*)d_in[2];
    float* out = (float*)d_out;
    char* ws = (char*)d_ws;

    float* pkF = (float*)ws;                              // 2 KB
    unsigned* red = (unsigned*)(ws + 8192);               // 512 KB
    unsigned* pk = (unsigned*)(ws + 8192 + 524288);       // 8 MB
    const size_t need = 8192 + 524288 + (size_t)NBLK * PK_CELLS * sizeof(unsigned);

    if (ws_size >= need) {
        kernA<false><<<NBLK, NTHR, 0, stream>>>(in, tg, pw, pk, pkF, nullptr, nullptr);
        kernB1<<<(NGRP * 1024) / 256, 256, 0, stream>>>(pk, red);
        kernBC<<<1, 1024, 0, stream>>>(red, pkF, out);
    } else {
        // fallback: needs only ~41 KB of workspace
        unsigned* gS = (unsigned*)(ws + 8192);
        unsigned* gP = gS + 4096;
        hipMemsetAsync(ws + 8192, 0, 2 * 4096 * sizeof(unsigned), stream);
        kernA<true><<<NBLK, NTHR, 0, stream>>>(in, tg, pw, nullptr, pkF, gS, gP);
        kernW<<<1, 1024, 0, stream>>>(gS, gP, pkF, out);
    }
}